// Round 3
// baseline (146.016 us; speedup 1.0000x reference)
//
#include <hip/hip_runtime.h>
#include <hip/hip_bf16.h>
#include <stdint.h>

#define B_ 8
#define S_ 1024
#define NH_ 16
#define D_ 64
#define H_ 1024
#define M_TOT (B_*S_)
#define LOG2E 1.44269504088896f

typedef __attribute__((ext_vector_type(8))) short short8;
typedef __attribute__((ext_vector_type(4))) float f32x4;
typedef __attribute__((ext_vector_type(16))) float f32x16;

#if __has_builtin(__builtin_amdgcn_exp2f)
#define EXP2(x) __builtin_amdgcn_exp2f(x)
#else
#define EXP2(x) __expf((x) * 0.69314718056f)
#endif

static __device__ __forceinline__ unsigned short f2bf(float f) {
  union { float f; unsigned u; } c; c.f = f;
  unsigned u = c.u;
  return (unsigned short)((u + 0x7fffu + ((u >> 16) & 1u)) >> 16);
}

static __device__ __forceinline__ void gld_lds16(void* lds, const void* g) {
  __builtin_amdgcn_global_load_lds((const __attribute__((address_space(1))) unsigned*)g,
                                   (__attribute__((address_space(3))) unsigned*)lds, 16, 0, 0);
}

#define WAIT_LGKM0() asm volatile("s_waitcnt lgkmcnt(0)" ::: "memory")
#define WAIT_VM(n)   asm volatile("s_waitcnt vmcnt(" #n ")" ::: "memory")
#define SBAR()       __builtin_amdgcn_s_barrier()
#define SCHED0()     __builtin_amdgcn_sched_barrier(0)

// ---------------- kernel 1: f32 -> bf16 conversion (X and the 3 weights) ----
__global__ void cvt_f32_bf16(const float* __restrict__ X,
                             const float* __restrict__ Wq,
                             const float* __restrict__ Wk,
                             const float* __restrict__ Wv,
                             unsigned short* __restrict__ Xbf,
                             unsigned short* __restrict__ Wbf) {
  const long long NX = (long long)M_TOT * H_;
  const long long NW = (long long)H_ * H_;
  long long t = (long long)blockIdx.x * blockDim.x + threadIdx.x;
  const long long stride = (long long)gridDim.x * blockDim.x;
  const long long total4 = (NX + 3 * NW) >> 2;
  for (; t < total4; t += stride) {
    long long e = t << 2;
    const float* src; unsigned short* dst;
    if (e < NX) { src = X + e; dst = Xbf + e; }
    else {
      long long r = e - NX;
      int w = (int)(r / NW);
      long long o = r - (long long)w * NW;
      src = (w == 0 ? Wq : (w == 1 ? Wk : Wv)) + o;
      dst = Wbf + (long long)w * NW + o;
    }
    float4 v = *(const float4*)src;
    ushort4 u;
    u.x = f2bf(v.x); u.y = f2bf(v.y); u.z = f2bf(v.z); u.w = f2bf(v.w);
    *(ushort4*)dst = u;
  }
}

// ---------------- kernel 2: QKV projection GEMM (phase-pipelined) ----------
// Tile 256(M) x 128(N) x 64(K). 8 waves (wm=w>>1: 4 M-strips of 64,
// wn=w&1: 2 N-strips of 64). Per-wave output 64x64 = acc[4][4] 16x16 frags.
// 3 LDS K-tile buffers (48KB each: A 32KB + B 16KB), counted vmcnt pipeline:
//   tile t in buf t%3; during mini-iter t, phases 1-3 stage tile t+2 into
//   buf (t+2)%3 (last read at mini-iter t-1); phase-4 vmcnt(6) leaves tile
//   t+2's 6 loads in flight while guaranteeing tile t+1 resident.
// z=0:Q (scaled /8*log2e, [b,h,s,d]) z=1:K z=2:V^T ([b,h,d,s]) via swapped
// operand roles (A<-W region, B<-X region).
#define QBM 256
#define QBN 128
#define QBK 64
#define BUFSZ 49152   /* A 32KB + B 16KB */

__global__ __launch_bounds__(512, 2) void qkv_gemm(
    const unsigned short* __restrict__ Xbf,
    const unsigned short* __restrict__ Wbf,
    const float* __restrict__ bq, const float* __restrict__ bk,
    const float* __restrict__ bv,
    unsigned short* __restrict__ Qo, unsigned short* __restrict__ Ko,
    unsigned short* __restrict__ Vt) {
  __shared__ char lds[3 * BUFSZ];   // 144 KB

  const int tid = threadIdx.x;
  const int w = tid >> 6;
  const int l = tid & 63;
  const int lrow = l & 15, lgrp = l >> 4;
  const int wm = w >> 1, wn = w & 1;

  // bijective XCD swizzle: 768 blocks, 96 per XCD; consecutive ids on one
  // XCD share (n,z) => W-panel (256KB) stays hot in that XCD's L2.
  const int orig = blockIdx.x;
  const int id = (orig & 7) * 96 + (orig >> 3);
  const int mtile = (id & 31) * QBM;
  const int rest = id >> 5;
  const int ntile = (rest & 7) * QBN;
  const int z = rest >> 3;

  const unsigned short* Wz = Wbf + (long long)z * H_ * H_;

  // staging: A chunks j=0..31 (8 rows each), B chunks j=0..15
  const int srow = l >> 3;
  const int sslot = l & 7;
  auto stageA = [&](char* buf, int j, int k0) {
    int row = j * 8 + srow;
    int so = (sslot ^ (row & 7)) * 8;
    gld_lds16(buf + j * 1024, Xbf + (long long)(mtile + row) * H_ + k0 + so);
  };
  auto stageB = [&](char* buf, int j, int k0) {
    int row = j * 8 + srow;
    int so = (sslot ^ (row & 7)) * 8;
    gld_lds16(buf + 32768 + j * 1024, Wz + (long long)(ntile + row) * H_ + k0 + so);
  };

  // fragment reads (A-operand / B-operand, z==2 swaps regions & strips)
  const int strA = (z == 2 ? wn : wm) * 64;
  const int strB = (z == 2 ? wm : wn) * 64;
  const int offA = (z == 2) ? 32768 : 0;
  const int offB = (z == 2) ? 0 : 32768;
  auto rdA = [&](char* buf, int mh, int sub, int ks) -> short8 {
    int r = strA + mh * 32 + sub * 16 + lrow;
    return *(const short8*)(buf + offA + r * 128 + (((ks * 4 + lgrp) ^ (r & 7)) * 16));
  };
  auto rdB = [&](char* buf, int nh, int sub, int ks) -> short8 {
    int r = strB + nh * 32 + sub * 16 + lrow;
    return *(const short8*)(buf + offB + r * 128 + (((ks * 4 + lgrp) ^ (r & 7)) * 16));
  };

  f32x4 acc[4][4];
  f32x4 zero = {0.f, 0.f, 0.f, 0.f};
  #pragma unroll
  for (int i = 0; i < 4; ++i)
    #pragma unroll
    for (int j = 0; j < 4; ++j) acc[i][j] = zero;

  // prologue: stage tiles 0 (buf0) and 1 (buf1)
  {
    char* b0p = lds;
    char* b1p = lds + BUFSZ;
    #pragma unroll
    for (int c = 0; c < 4; ++c) stageA(b0p, w * 4 + c, 0);
    stageB(b0p, w * 2 + 0, 0); stageB(b0p, w * 2 + 1, 0);
    #pragma unroll
    for (int c = 0; c < 4; ++c) stageA(b1p, w * 4 + c, QBK);
    stageB(b1p, w * 2 + 0, QBK); stageB(b1p, w * 2 + 1, QBK);
  }
  WAIT_VM(6);     // tile 0 resident, tile 1 in flight
  SBAR();

  #pragma unroll 1
  for (int t = 0; t < 16; ++t) {
    char* buf  = lds + (t % 3) * BUFSZ;
    char* nbuf = lds + ((t + 2) % 3) * BUFSZ;
    const int k0n = (t + 2) * QBK;
    const bool st = (t + 2 < 16);

    short8 af[2][2], b0[2][2], b1[2][2];

    // ---- phase 1: quadrant (mh0, nh0)
    #pragma unroll
    for (int sub = 0; sub < 2; ++sub)
      #pragma unroll
      for (int ks = 0; ks < 2; ++ks) {
        af[sub][ks] = rdA(buf, 0, sub, ks);
        b0[sub][ks] = rdB(buf, 0, sub, ks);
      }
    if (st) { stageA(nbuf, w * 4 + 0, k0n); stageA(nbuf, w * 4 + 1, k0n); }
    SBAR();
    WAIT_LGKM0(); SCHED0();
    __builtin_amdgcn_s_setprio(1);
    #pragma unroll
    for (int sa = 0; sa < 2; ++sa)
      #pragma unroll
      for (int sb = 0; sb < 2; ++sb)
        #pragma unroll
        for (int ks = 0; ks < 2; ++ks)
          acc[sa][sb] = __builtin_amdgcn_mfma_f32_16x16x32_bf16(
              af[sa][ks], b0[sb][ks], acc[sa][sb], 0, 0, 0);
    __builtin_amdgcn_s_setprio(0);
    SBAR();

    // ---- phase 2: quadrant (mh0, nh1)
    #pragma unroll
    for (int sub = 0; sub < 2; ++sub)
      #pragma unroll
      for (int ks = 0; ks < 2; ++ks)
        b1[sub][ks] = rdB(buf, 1, sub, ks);
    if (st) { stageA(nbuf, w * 4 + 2, k0n); stageA(nbuf, w * 4 + 3, k0n); }
    SBAR();
    WAIT_LGKM0(); SCHED0();
    __builtin_amdgcn_s_setprio(1);
    #pragma unroll
    for (int sa = 0; sa < 2; ++sa)
      #pragma unroll
      for (int sb = 0; sb < 2; ++sb)
        #pragma unroll
        for (int ks = 0; ks < 2; ++ks)
          acc[sa][2 + sb] = __builtin_amdgcn_mfma_f32_16x16x32_bf16(
              af[sa][ks], b1[sb][ks], acc[sa][2 + sb], 0, 0, 0);
    __builtin_amdgcn_s_setprio(0);
    SBAR();

    // ---- phase 3: quadrant (mh1, nh1)
    #pragma unroll
    for (int sub = 0; sub < 2; ++sub)
      #pragma unroll
      for (int ks = 0; ks < 2; ++ks)
        af[sub][ks] = rdA(buf, 1, sub, ks);
    if (st) { stageB(nbuf, w * 2 + 0, k0n); stageB(nbuf, w * 2 + 1, k0n); }
    SBAR();
    WAIT_LGKM0(); SCHED0();
    __builtin_amdgcn_s_setprio(1);
    #pragma unroll
    for (int sa = 0; sa < 2; ++sa)
      #pragma unroll
      for (int sb = 0; sb < 2; ++sb)
        #pragma unroll
        for (int ks = 0; ks < 2; ++ks)
          acc[2 + sa][2 + sb] = __builtin_amdgcn_mfma_f32_16x16x32_bf16(
              af[sa][ks], b1[sb][ks], acc[2 + sa][2 + sb], 0, 0, 0);
    __builtin_amdgcn_s_setprio(0);
    SBAR();

    // ---- phase 4: quadrant (mh1, nh0) — no ds_reads (regs alive)
    __builtin_amdgcn_s_setprio(1);
    #pragma unroll
    for (int sa = 0; sa < 2; ++sa)
      #pragma unroll
      for (int sb = 0; sb < 2; ++sb)
        #pragma unroll
        for (int ks = 0; ks < 2; ++ks)
          acc[2 + sa][sb] = __builtin_amdgcn_mfma_f32_16x16x32_bf16(
              af[sa][ks], b0[sb][ks], acc[2 + sa][sb], 0, 0, 0);
    __builtin_amdgcn_s_setprio(0);
    if (t < 14) { WAIT_VM(6); } else { WAIT_VM(0); }
    SBAR();
  }

  // ---- epilogue
  const float* bias = (z == 0) ? bq : (z == 1) ? bk : bv;
  if (z != 2) {
    unsigned short* O = (z == 0) ? Qo : Ko;
    #pragma unroll
    for (int in = 0; in < 4; ++in) {
      int n = ntile + wn * 64 + in * 16 + lrow;
      float bv_ = bias[n];
      int h = n >> 6, d = n & 63;
      #pragma unroll
      for (int im = 0; im < 4; ++im)
        #pragma unroll
        for (int r = 0; r < 4; ++r) {
          int m = mtile + wm * 64 + im * 16 + lgrp * 4 + r;
          float val = acc[im][in][r] + bv_;
          if (z == 0) val *= 0.125f * LOG2E;
          int b = m >> 10, s = m & 1023;
          O[(((long long)(b * NH_ + h)) * S_ + s) * D_ + d] = f2bf(val);
        }
    }
  } else {
    #pragma unroll
    for (int im = 0; im < 4; ++im)
      #pragma unroll
      for (int r = 0; r < 4; ++r) {
        int nfull = ntile + wn * 64 + im * 16 + lgrp * 4 + r;   // d-side (A rows)
        float bv_ = bias[nfull];
        int h = nfull >> 6, d = nfull & 63;
        #pragma unroll
        for (int in = 0; in < 4; ++in) {
          int mfull = mtile + wm * 64 + in * 16 + lrow;          // s-side (B rows)
          float val = acc[im][in][r] + bv_;
          int b = mfull >> 10, s = mfull & 1023;
          Vt[(((long long)(b * NH_ + h)) * D_ + d) * S_ + s] = f2bf(val);
        }
      }
  }
}

// ---------------- kernel 3: fused flash attention (32x32 swapped) ----------
__global__ __launch_bounds__(256, 2) void attn_fused(
    const unsigned short* __restrict__ Qbf,
    const unsigned short* __restrict__ Kbf,
    const unsigned short* __restrict__ Vtb,
    const float* __restrict__ mask,
    float* __restrict__ out) {
  __shared__ char lds[32768];                 // 2 x (K 8KB | V^T 8KB)
  const int tid = threadIdx.x, w = tid >> 6, l = tid & 63;
  const int l31 = l & 31, h = l >> 5;

  const int lid = blockIdx.x;                 // 0..511
  const int xcd = lid & 7, k8 = lid >> 3;
  const int bh = xcd * 16 + (k8 >> 2);
  const int qt = k8 & 3;
  const int b = bh >> 4, hd = bh & 15;
  const int q0 = qt * 256 + w * 64;

  const unsigned short* Kg = Kbf + (long long)bh * S_ * D_;
  const unsigned short* Vg = Vtb + (long long)bh * D_ * S_;
  const float* mrow = mask + b * S_;

  {
    const int row = (w * 2) * 8 + (l >> 3);
    const int row1 = (w * 2 + 1) * 8 + (l >> 3);
    const int so = ((l & 7) ^ (row & 7)) * 8;
    const int so1 = ((l & 7) ^ (row1 & 7)) * 8;
    gld_lds16(lds + (w * 2) * 1024,        Kg + (long long)row * D_ + so);
    gld_lds16(lds + (w * 2 + 1) * 1024,    Kg + (long long)row1 * D_ + so1);
    gld_lds16(lds + 8192 + (w * 2) * 1024, Vg + (long long)row * S_ + so);
    gld_lds16(lds + 8192 + (w * 2 + 1) * 1024, Vg + (long long)row1 * S_ + so1);
  }

  short8 qf[2][4];
  #pragma unroll
  for (int qb = 0; qb < 2; ++qb)
    #pragma unroll
    for (int ks = 0; ks < 4; ++ks)
      qf[qb][ks] = *(const short8*)(Qbf + ((long long)bh * S_ + q0 + qb * 32 + l31) * D_ + ks * 16 + 8 * h);

  f32x16 acc[2][2];
  #pragma unroll
  for (int db = 0; db < 2; ++db)
    #pragma unroll
    for (int qb = 0; qb < 2; ++qb)
      #pragma unroll
      for (int r = 0; r < 16; ++r) acc[db][qb][r] = 0.f;
  float m_run[2] = {-1e30f, -1e30f};
  float l_run[2] = {0.f, 0.f};

  __syncthreads();

  for (int kt = 0; kt < S_ / 64; ++kt) {
    const int p = kt & 1;
    char* ldsK = lds + p * 16384;
    char* ldsV = ldsK + 8192;
    const int key0 = kt * 64;

    if (kt < S_ / 64 - 1) {
      char* nb = lds + (p ^ 1) * 16384;
      const int nk0 = key0 + 64;
      #pragma unroll
      for (int t = 0; t < 2; ++t) {
        int j = w * 2 + t;
        int row = j * 8 + (l >> 3);
        int so = ((l & 7) ^ (row & 7)) * 8;
        gld_lds16(nb + j * 1024,        Kg + (long long)(nk0 + row) * D_ + so);
        gld_lds16(nb + 8192 + j * 1024, Vg + (long long)row * S_ + nk0 + so);
      }
    }

    f32x16 sc[2][2];
    #pragma unroll
    for (int kb = 0; kb < 2; ++kb)
      #pragma unroll
      for (int qb = 0; qb < 2; ++qb)
        #pragma unroll
        for (int r = 0; r < 16; ++r) sc[kb][qb][r] = 0.f;

    #pragma unroll
    for (int kb = 0; kb < 2; ++kb) {
      short8 kf[4];
      #pragma unroll
      for (int ks = 0; ks < 4; ++ks) {
        int row = kb * 32 + l31;
        int g = (2 * ks + h) ^ (row & 7);
        kf[ks] = *(const short8*)(ldsK + row * 128 + g * 16);
      }
      __builtin_amdgcn_s_setprio(1);
      #pragma unroll
      for (int qb = 0; qb < 2; ++qb)
        #pragma unroll
        for (int ks = 0; ks < 4; ++ks)
          sc[kb][qb] = __builtin_amdgcn_mfma_f32_32x32x16_bf16(
              kf[ks], qf[qb][ks], sc[kb][qb], 0, 0, 0);
      __builtin_amdgcn_s_setprio(0);
    }

    short8 pfrag[2][4];
    #pragma unroll
    for (int qb = 0; qb < 2; ++qb) {
      float sv[32];
      #pragma unroll
      for (int kb = 0; kb < 2; ++kb)
        #pragma unroll
        for (int rg = 0; rg < 4; ++rg) {
          f32x4 m4 = *(const f32x4*)(mrow + key0 + kb * 32 + rg * 8 + 4 * h);
          #pragma unroll
          for (int c = 0; c < 4; ++c)
            sv[kb * 16 + rg * 4 + c] = fmaf(m4[c], LOG2E, sc[kb][qb][rg * 4 + c]);
        }
      float r16[16];
      #pragma unroll
      for (int i = 0; i < 16; ++i) r16[i] = fmaxf(sv[i], sv[i + 16]);
      #pragma unroll
      for (int i = 0; i < 8; ++i) r16[i] = fmaxf(r16[i], r16[i + 8]);
      #pragma unroll
      for (int i = 0; i < 4; ++i) r16[i] = fmaxf(r16[i], r16[i + 4]);
      float pm = fmaxf(fmaxf(r16[0], r16[1]), fmaxf(r16[2], r16[3]));
      pm = fmaxf(pm, __shfl_xor(pm, 32));
      if (!__all(pm - m_run[qb] <= 11.5f)) {
        float mn = fmaxf(m_run[qb], pm);
        float rs = EXP2(m_run[qb] - mn);
        m_run[qb] = mn;
        l_run[qb] *= rs;
        #pragma unroll
        for (int db = 0; db < 2; ++db)
          #pragma unroll
          for (int r = 0; r < 16; ++r) acc[db][qb][r] *= rs;
      }
      const float mcur = m_run[qb];
      #pragma unroll
      for (int i = 0; i < 32; ++i) sv[i] = EXP2(sv[i] - mcur);
      #pragma unroll
      for (int i = 0; i < 16; ++i) r16[i] = sv[i] + sv[i + 16];
      #pragma unroll
      for (int i = 0; i < 8; ++i) r16[i] = r16[i] + r16[i + 8];
      #pragma unroll
      for (int i = 0; i < 4; ++i) r16[i] = r16[i] + r16[i + 4];
      float ps = (r16[0] + r16[1]) + (r16[2] + r16[3]);
      ps += __shfl_xor(ps, 32);
      l_run[qb] += ps;

      unsigned Wd[8][2];
      #pragma unroll
      for (int j = 0; j < 8; ++j) {
        int base = (j >> 2) * 16 + (j & 3) * 4;
        asm("v_cvt_pk_bf16_f32 %0, %1, %2" : "=v"(Wd[j][0]) : "v"(sv[base + 0]), "v"(sv[base + 1]));
        asm("v_cvt_pk_bf16_f32 %0, %1, %2" : "=v"(Wd[j][1]) : "v"(sv[base + 2]), "v"(sv[base + 3]));
      }
      #pragma unroll
      for (int ks = 0; ks < 4; ++ks) {
        unsigned s0 = h ? Wd[2 * ks][0] : Wd[2 * ks + 1][0];
        unsigned s1 = h ? Wd[2 * ks][1] : Wd[2 * ks + 1][1];
        unsigned r0 = __shfl_xor(s0, 32);
        unsigned r1 = __shfl_xor(s1, 32);
        unsigned o0 = h ? Wd[2 * ks + 1][0] : Wd[2 * ks][0];
        unsigned o1 = h ? Wd[2 * ks + 1][1] : Wd[2 * ks][1];
        union { unsigned u[4]; short8 s; } fu;
        fu.u[0] = h ? r0 : o0;
        fu.u[1] = h ? r1 : o1;
        fu.u[2] = h ? o0 : r0;
        fu.u[3] = h ? o1 : r1;
        pfrag[qb][ks] = fu.s;
      }
    }

    #pragma unroll
    for (int db = 0; db < 2; ++db) {
      short8 vf[4];
      #pragma unroll
      for (int ks = 0; ks < 4; ++ks) {
        int row = db * 32 + l31;
        int g = (2 * ks + h) ^ (row & 7);
        vf[ks] = *(const short8*)(ldsV + row * 128 + g * 16);
      }
      __builtin_amdgcn_s_setprio(1);
      #pragma unroll
      for (int qb = 0; qb < 2; ++qb)
        #pragma unroll
        for (int ks = 0; ks < 4; ++ks)
          acc[db][qb] = __builtin_amdgcn_mfma_f32_32x32x16_bf16(
              vf[ks], pfrag[qb][ks], acc[db][qb], 0, 0, 0);
      __builtin_amdgcn_s_setprio(0);
    }

    __syncthreads();
  }

  #pragma unroll
  for (int qb = 0; qb < 2; ++qb) {
    float inv = 1.0f / l_run[qb];
    int q = q0 + qb * 32 + l31;
    float* orow = out + ((long long)b * S_ + q) * H_ + hd * D_;
    #pragma unroll
    for (int db = 0; db < 2; ++db)
      #pragma unroll
      for (int rg = 0; rg < 4; ++rg) {
        f32x4 v4;
        #pragma unroll
        for (int c = 0; c < 4; ++c) v4[c] = acc[db][qb][rg * 4 + c] * inv;
        *(f32x4*)(orow + db * 32 + rg * 8 + 4 * h) = v4;
      }
  }
}

// ---------------- launcher -------------------------------------------------
extern "C" void kernel_launch(void* const* d_in, const int* in_sizes, int n_in,
                              void* d_out, int out_size, void* d_ws, size_t ws_size,
                              hipStream_t stream) {
  const float* X    = (const float*)d_in[0];
  const float* mask = (const float*)d_in[1];
  const float* Wq   = (const float*)d_in[2];
  const float* bq   = (const float*)d_in[3];
  const float* Wk   = (const float*)d_in[4];
  const float* bk   = (const float*)d_in[5];
  const float* Wv   = (const float*)d_in[6];
  const float* bv   = (const float*)d_in[7];
  float* out = (float*)d_out;

  char* ws = (char*)d_ws;
  unsigned short* Xbf = (unsigned short*)ws;                 // 16 MB
  unsigned short* Wbf = (unsigned short*)(ws + 16777216);    //  6 MB
  unsigned short* Qb  = (unsigned short*)(ws + 23068672);    // 16 MB
  unsigned short* Kb  = (unsigned short*)(ws + 39845888);    // 16 MB
  unsigned short* Vt  = (unsigned short*)(ws + 56623104);    // 16 MB

  hipLaunchKernelGGL(cvt_f32_bf16, dim3(2048), dim3(256), 0, stream,
                     X, Wq, Wk, Wv, Xbf, Wbf);
  hipLaunchKernelGGL(qkv_gemm, dim3(768), dim3(512), 0, stream,
                     Xbf, Wbf, bq, bk, bv, Qb, Kb, Vt);
  hipLaunchKernelGGL(attn_fused, dim3(512), dim3(256), 0, stream,
                     Qb, Kb, Vt, mask, out);
}

// Round 4
// 132.623 us; speedup vs baseline: 1.1010x; 1.1010x over previous
//
#include <hip/hip_runtime.h>
#include <hip/hip_bf16.h>
#include <stdint.h>

#define B_ 8
#define S_ 1024
#define NH_ 16
#define D_ 64
#define H_ 1024
#define M_TOT (B_*S_)
#define LOG2E 1.44269504088896f

typedef __attribute__((ext_vector_type(8))) short short8;
typedef __attribute__((ext_vector_type(4))) float f32x4;
typedef __attribute__((ext_vector_type(16))) float f32x16;

#if __has_builtin(__builtin_amdgcn_exp2f)
#define EXP2(x) __builtin_amdgcn_exp2f(x)
#else
#define EXP2(x) __expf((x) * 0.69314718056f)
#endif

static __device__ __forceinline__ unsigned short f2bf(float f) {
  union { float f; unsigned u; } c; c.f = f;
  unsigned u = c.u;
  return (unsigned short)((u + 0x7fffu + ((u >> 16) & 1u)) >> 16);
}

static __device__ __forceinline__ void gld_lds16(void* lds, const void* g) {
  __builtin_amdgcn_global_load_lds((const __attribute__((address_space(1))) unsigned*)g,
                                   (__attribute__((address_space(3))) unsigned*)lds, 16, 0, 0);
}

#define WAIT_LGKM0() asm volatile("s_waitcnt lgkmcnt(0)" ::: "memory")
#define WAIT_VM(n)   asm volatile("s_waitcnt vmcnt(" #n ")" ::: "memory")
#define SBAR()       __builtin_amdgcn_s_barrier()
#define SCHED0()     __builtin_amdgcn_sched_barrier(0)

// ---------------- kernel 1: f32 -> bf16 conversion (X and the 3 weights) ----
__global__ void cvt_f32_bf16(const float* __restrict__ X,
                             const float* __restrict__ Wq,
                             const float* __restrict__ Wk,
                             const float* __restrict__ Wv,
                             unsigned short* __restrict__ Xbf,
                             unsigned short* __restrict__ Wbf) {
  const long long NX = (long long)M_TOT * H_;
  const long long NW = (long long)H_ * H_;
  long long t = (long long)blockIdx.x * blockDim.x + threadIdx.x;
  const long long stride = (long long)gridDim.x * blockDim.x;
  const long long total4 = (NX + 3 * NW) >> 2;
  for (; t < total4; t += stride) {
    long long e = t << 2;
    const float* src; unsigned short* dst;
    if (e < NX) { src = X + e; dst = Xbf + e; }
    else {
      long long r = e - NX;
      int w = (int)(r / NW);
      long long o = r - (long long)w * NW;
      src = (w == 0 ? Wq : (w == 1 ? Wk : Wv)) + o;
      dst = Wbf + (long long)w * NW + o;
    }
    float4 v = *(const float4*)src;
    ushort4 u;
    u.x = f2bf(v.x); u.y = f2bf(v.y); u.z = f2bf(v.z); u.w = f2bf(v.w);
    *(ushort4*)dst = u;
  }
}

// ---------------- kernel 2: QKV projection GEMM (depth-2 counted-vmcnt) ----
// Tile 128(M) x 256(N) x 64(K). 8 waves: wm=w>>2 (2 M-strips of 64),
// wn=w&3 (4 N-strips of 64). Per-wave output 64x64 = acc[4][4] 16x16 frags.
// 3 LDS buffers (48KB: A 16KB rows0..127 | B 32KB rows0..255).
// Per-wave ledger: 6 loads/tile (A:2, B:4). Tile t lives in buf t%3; during
// tile t we stage tile t+2 (3 loads per phase). Boundary vmcnt(6) waits
// tile t+1's 6 loads, leaves t+2's 6 in flight. 2 phases/tile, 16 MFMA each.
// z=0:Q (scaled /8*log2e) z=1:K  z=2:V^T via swapped operand roles.
#define QBM 128
#define QBN 256
#define QBK 64
#define BUFSZ 49152

__global__ __launch_bounds__(512, 2) void qkv_gemm(
    const unsigned short* __restrict__ Xbf,
    const unsigned short* __restrict__ Wbf,
    const float* __restrict__ bq, const float* __restrict__ bk,
    const float* __restrict__ bv,
    unsigned short* __restrict__ Qo, unsigned short* __restrict__ Ko,
    unsigned short* __restrict__ Vt) {
  __shared__ char lds[3 * BUFSZ];   // 144 KB

  const int tid = threadIdx.x;
  const int w = tid >> 6;
  const int l = tid & 63;
  const int lrow = l & 15, lgrp = l >> 4;
  const int wm = w >> 2, wn = w & 3;

  // L2-correct swizzle: 768 blocks = 3 rounds x 256. XCD x (=orig&7) in
  // round z owns m-tiles [8x,8x+8) x all 4 n-tiles: working set =
  // 2MB A-strip + 2MB W_z = one XCD's 4MB L2.
  const int orig = blockIdx.x;
  const int xcd = orig & 7;
  const int slot = orig >> 3;          // 0..95
  const int z = slot >> 5;             // 0..2 (round)
  const int i = slot & 31;
  const int mtile = (xcd * 8 + (i >> 2)) * QBM;
  const int ntile = (i & 3) * QBN;

  const unsigned short* Wz = Wbf + (long long)z * H_ * H_;

  // staging: A chunks j=0..15 (8 rows each, 1KB), B chunks j=0..31
  const int srow = l >> 3;
  const int sslot = l & 7;
  auto stageA = [&](char* buf, int j, int k0) {
    int row = j * 8 + srow;
    int so = (sslot ^ (row & 7)) * 8;
    gld_lds16(buf + j * 1024, Xbf + (long long)(mtile + row) * H_ + k0 + so);
  };
  auto stageB = [&](char* buf, int j, int k0) {
    int row = j * 8 + srow;
    int so = (sslot ^ (row & 7)) * 8;
    gld_lds16(buf + 16384 + j * 1024, Wz + (long long)(ntile + row) * H_ + k0 + so);
  };

  // fragment reads (z==2 swaps operand regions & strips)
  const int strA = (z == 2 ? wn : wm) * 64;
  const int strB = (z == 2 ? wm : wn) * 64;
  const int offA = (z == 2) ? 16384 : 0;
  const int offB = (z == 2) ? 0 : 16384;
  auto rdA = [&](char* buf, int fi, int ks) -> short8 {
    int r = strA + fi * 16 + lrow;
    return *(const short8*)(buf + offA + r * 128 + (((ks * 4 + lgrp) ^ (r & 7)) * 16));
  };
  auto rdB = [&](char* buf, int fi, int ks) -> short8 {
    int r = strB + fi * 16 + lrow;
    return *(const short8*)(buf + offB + r * 128 + (((ks * 4 + lgrp) ^ (r & 7)) * 16));
  };

  f32x4 acc[4][4];
  f32x4 zero = {0.f, 0.f, 0.f, 0.f};
  #pragma unroll
  for (int a = 0; a < 4; ++a)
    #pragma unroll
    for (int c = 0; c < 4; ++c) acc[a][c] = zero;

  // prologue: stage tiles 0 (buf0) and 1 (buf1); 6 loads each per wave
  {
    char* b0p = lds;
    char* b1p = lds + BUFSZ;
    stageA(b0p, 2 * w + 0, 0); stageA(b0p, 2 * w + 1, 0);
    #pragma unroll
    for (int c = 0; c < 4; ++c) stageB(b0p, 4 * w + c, 0);
    stageA(b1p, 2 * w + 0, QBK); stageA(b1p, 2 * w + 1, QBK);
    #pragma unroll
    for (int c = 0; c < 4; ++c) stageB(b1p, 4 * w + c, QBK);
  }
  WAIT_VM(6);     // tile 0 resident (my 6 oldest), tile 1 in flight
  SBAR();

  #pragma unroll 1
  for (int t = 0; t < 16; ++t) {
    char* buf  = lds + (t % 3) * BUFSZ;
    char* nbuf = lds + ((t + 2) % 3) * BUFSZ;
    const int k0n = (t + 2) * QBK;
    const bool st = (t + 2 < 16);

    short8 af[4][2], bf[2][2];

    // ---- phase 1: n-half 0  (12 ds_read, 16 MFMA)
    #pragma unroll
    for (int fi = 0; fi < 4; ++fi)
      #pragma unroll
      for (int ks = 0; ks < 2; ++ks) af[fi][ks] = rdA(buf, fi, ks);
    #pragma unroll
    for (int fi = 0; fi < 2; ++fi)
      #pragma unroll
      for (int ks = 0; ks < 2; ++ks) bf[fi][ks] = rdB(buf, fi, ks);
    if (st) { stageA(nbuf, 2 * w + 0, k0n); stageA(nbuf, 2 * w + 1, k0n);
              stageB(nbuf, 4 * w + 0, k0n); }
    SBAR();
    WAIT_LGKM0(); SCHED0();
    __builtin_amdgcn_s_setprio(1);
    #pragma unroll
    for (int im = 0; im < 4; ++im)
      #pragma unroll
      for (int in = 0; in < 2; ++in)
        #pragma unroll
        for (int ks = 0; ks < 2; ++ks)
          acc[im][in] = __builtin_amdgcn_mfma_f32_16x16x32_bf16(
              af[im][ks], bf[in][ks], acc[im][in], 0, 0, 0);
    __builtin_amdgcn_s_setprio(0);
    SBAR();

    // ---- phase 2: n-half 1  (4 ds_read, 16 MFMA; af regs stay live)
    #pragma unroll
    for (int fi = 0; fi < 2; ++fi)
      #pragma unroll
      for (int ks = 0; ks < 2; ++ks) bf[fi][ks] = rdB(buf, 2 + fi, ks);
    if (st) { stageB(nbuf, 4 * w + 1, k0n); stageB(nbuf, 4 * w + 2, k0n);
              stageB(nbuf, 4 * w + 3, k0n); }
    SBAR();
    WAIT_LGKM0(); SCHED0();
    __builtin_amdgcn_s_setprio(1);
    #pragma unroll
    for (int im = 0; im < 4; ++im)
      #pragma unroll
      for (int in = 0; in < 2; ++in)
        #pragma unroll
        for (int ks = 0; ks < 2; ++ks)
          acc[im][2 + in] = __builtin_amdgcn_mfma_f32_16x16x32_bf16(
              af[im][ks], bf[in][ks], acc[im][2 + in], 0, 0, 0);
    __builtin_amdgcn_s_setprio(0);
    if (t < 14) { WAIT_VM(6); } else { WAIT_VM(0); }
    SBAR();
  }

  // ---- epilogue
  const float* bias = (z == 0) ? bq : (z == 1) ? bk : bv;
  if (z != 2) {
    unsigned short* O = (z == 0) ? Qo : Ko;
    #pragma unroll
    for (int in = 0; in < 4; ++in) {
      int n = ntile + wn * 64 + in * 16 + lrow;
      float bv_ = bias[n];
      int h = n >> 6, d = n & 63;
      #pragma unroll
      for (int im = 0; im < 4; ++im)
        #pragma unroll
        for (int r = 0; r < 4; ++r) {
          int m = mtile + wm * 64 + im * 16 + lgrp * 4 + r;
          float val = acc[im][in][r] + bv_;
          if (z == 0) val *= 0.125f * LOG2E;
          int b = m >> 10, s = m & 1023;
          O[(((long long)(b * NH_ + h)) * S_ + s) * D_ + d] = f2bf(val);
        }
    }
  } else {
    #pragma unroll
    for (int im = 0; im < 4; ++im)
      #pragma unroll
      for (int r = 0; r < 4; ++r) {
        int nfull = ntile + wn * 64 + im * 16 + lgrp * 4 + r;   // d-side (W rows)
        float bv_ = bias[nfull];
        int h = nfull >> 6, d = nfull & 63;
        #pragma unroll
        for (int in = 0; in < 4; ++in) {
          int mfull = mtile + wm * 64 + in * 16 + lrow;          // s-side (X rows)
          float val = acc[im][in][r] + bv_;
          int b = mfull >> 10, s = mfull & 1023;
          Vt[(((long long)(b * NH_ + h)) * D_ + d) * S_ + s] = f2bf(val);
        }
      }
  }
}

// ---------------- kernel 3: fused flash attention (32x32 swapped) ----------
__global__ __launch_bounds__(256, 2) void attn_fused(
    const unsigned short* __restrict__ Qbf,
    const unsigned short* __restrict__ Kbf,
    const unsigned short* __restrict__ Vtb,
    const float* __restrict__ mask,
    float* __restrict__ out) {
  __shared__ char lds[32768];                 // 2 x (K 8KB | V^T 8KB)
  const int tid = threadIdx.x, w = tid >> 6, l = tid & 63;
  const int l31 = l & 31, h = l >> 5;

  const int lid = blockIdx.x;                 // 0..511
  const int xcd = lid & 7, k8 = lid >> 3;
  const int bh = xcd * 16 + (k8 >> 2);
  const int qt = k8 & 3;
  const int b = bh >> 4, hd = bh & 15;
  const int q0 = qt * 256 + w * 64;

  const unsigned short* Kg = Kbf + (long long)bh * S_ * D_;
  const unsigned short* Vg = Vtb + (long long)bh * D_ * S_;
  const float* mrow = mask + b * S_;

  {
    const int row = (w * 2) * 8 + (l >> 3);
    const int row1 = (w * 2 + 1) * 8 + (l >> 3);
    const int so = ((l & 7) ^ (row & 7)) * 8;
    const int so1 = ((l & 7) ^ (row1 & 7)) * 8;
    gld_lds16(lds + (w * 2) * 1024,        Kg + (long long)row * D_ + so);
    gld_lds16(lds + (w * 2 + 1) * 1024,    Kg + (long long)row1 * D_ + so1);
    gld_lds16(lds + 8192 + (w * 2) * 1024, Vg + (long long)row * S_ + so);
    gld_lds16(lds + 8192 + (w * 2 + 1) * 1024, Vg + (long long)row1 * S_ + so1);
  }

  short8 qf[2][4];
  #pragma unroll
  for (int qb = 0; qb < 2; ++qb)
    #pragma unroll
    for (int ks = 0; ks < 4; ++ks)
      qf[qb][ks] = *(const short8*)(Qbf + ((long long)bh * S_ + q0 + qb * 32 + l31) * D_ + ks * 16 + 8 * h);

  f32x16 acc[2][2];
  #pragma unroll
  for (int db = 0; db < 2; ++db)
    #pragma unroll
    for (int qb = 0; qb < 2; ++qb)
      #pragma unroll
      for (int r = 0; r < 16; ++r) acc[db][qb][r] = 0.f;
  float m_run[2] = {-1e30f, -1e30f};
  float l_run[2] = {0.f, 0.f};

  __syncthreads();

  for (int kt = 0; kt < S_ / 64; ++kt) {
    const int p = kt & 1;
    char* ldsK = lds + p * 16384;
    char* ldsV = ldsK + 8192;
    const int key0 = kt * 64;

    if (kt < S_ / 64 - 1) {
      char* nb = lds + (p ^ 1) * 16384;
      const int nk0 = key0 + 64;
      #pragma unroll
      for (int t = 0; t < 2; ++t) {
        int j = w * 2 + t;
        int row = j * 8 + (l >> 3);
        int so = ((l & 7) ^ (row & 7)) * 8;
        gld_lds16(nb + j * 1024,        Kg + (long long)(nk0 + row) * D_ + so);
        gld_lds16(nb + 8192 + j * 1024, Vg + (long long)row * S_ + nk0 + so);
      }
    }

    f32x16 sc[2][2];
    #pragma unroll
    for (int kb = 0; kb < 2; ++kb)
      #pragma unroll
      for (int qb = 0; qb < 2; ++qb)
        #pragma unroll
        for (int r = 0; r < 16; ++r) sc[kb][qb][r] = 0.f;

    #pragma unroll
    for (int kb = 0; kb < 2; ++kb) {
      short8 kf[4];
      #pragma unroll
      for (int ks = 0; ks < 4; ++ks) {
        int row = kb * 32 + l31;
        int g = (2 * ks + h) ^ (row & 7);
        kf[ks] = *(const short8*)(ldsK + row * 128 + g * 16);
      }
      __builtin_amdgcn_s_setprio(1);
      #pragma unroll
      for (int qb = 0; qb < 2; ++qb)
        #pragma unroll
        for (int ks = 0; ks < 4; ++ks)
          sc[kb][qb] = __builtin_amdgcn_mfma_f32_32x32x16_bf16(
              kf[ks], qf[qb][ks], sc[kb][qb], 0, 0, 0);
      __builtin_amdgcn_s_setprio(0);
    }

    short8 pfrag[2][4];
    #pragma unroll
    for (int qb = 0; qb < 2; ++qb) {
      float sv[32];
      #pragma unroll
      for (int kb = 0; kb < 2; ++kb)
        #pragma unroll
        for (int rg = 0; rg < 4; ++rg) {
          f32x4 m4 = *(const f32x4*)(mrow + key0 + kb * 32 + rg * 8 + 4 * h);
          #pragma unroll
          for (int c = 0; c < 4; ++c)
            sv[kb * 16 + rg * 4 + c] = fmaf(m4[c], LOG2E, sc[kb][qb][rg * 4 + c]);
        }
      float r16[16];
      #pragma unroll
      for (int i = 0; i < 16; ++i) r16[i] = fmaxf(sv[i], sv[i + 16]);
      #pragma unroll
      for (int i = 0; i < 8; ++i) r16[i] = fmaxf(r16[i], r16[i + 8]);
      #pragma unroll
      for (int i = 0; i < 4; ++i) r16[i] = fmaxf(r16[i], r16[i + 4]);
      float pm = fmaxf(fmaxf(r16[0], r16[1]), fmaxf(r16[2], r16[3]));
      pm = fmaxf(pm, __shfl_xor(pm, 32));
      if (!__all(pm - m_run[qb] <= 11.5f)) {
        float mn = fmaxf(m_run[qb], pm);
        float rs = EXP2(m_run[qb] - mn);
        m_run[qb] = mn;
        l_run[qb] *= rs;
        #pragma unroll
        for (int db = 0; db < 2; ++db)
          #pragma unroll
          for (int r = 0; r < 16; ++r) acc[db][qb][r] *= rs;
      }
      const float mcur = m_run[qb];
      #pragma unroll
      for (int i = 0; i < 32; ++i) sv[i] = EXP2(sv[i] - mcur);
      #pragma unroll
      for (int i = 0; i < 16; ++i) r16[i] = sv[i] + sv[i + 16];
      #pragma unroll
      for (int i = 0; i < 8; ++i) r16[i] = r16[i] + r16[i + 8];
      #pragma unroll
      for (int i = 0; i < 4; ++i) r16[i] = r16[i] + r16[i + 4];
      float ps = (r16[0] + r16[1]) + (r16[2] + r16[3]);
      ps += __shfl_xor(ps, 32);
      l_run[qb] += ps;

      unsigned Wd[8][2];
      #pragma unroll
      for (int j = 0; j < 8; ++j) {
        int base = (j >> 2) * 16 + (j & 3) * 4;
        asm("v_cvt_pk_bf16_f32 %0, %1, %2" : "=v"(Wd[j][0]) : "v"(sv[base + 0]), "v"(sv[base + 1]));
        asm("v_cvt_pk_bf16_f32 %0, %1, %2" : "=v"(Wd[j][1]) : "v"(sv[base + 2]), "v"(sv[base + 3]));
      }
      #pragma unroll
      for (int ks = 0; ks < 4; ++ks) {
        unsigned s0 = h ? Wd[2 * ks][0] : Wd[2 * ks + 1][0];
        unsigned s1 = h ? Wd[2 * ks][1] : Wd[2 * ks + 1][1];
        unsigned r0 = __shfl_xor(s0, 32);
        unsigned r1 = __shfl_xor(s1, 32);
        unsigned o0 = h ? Wd[2 * ks + 1][0] : Wd[2 * ks][0];
        unsigned o1 = h ? Wd[2 * ks + 1][1] : Wd[2 * ks][1];
        union { unsigned u[4]; short8 s; } fu;
        fu.u[0] = h ? r0 : o0;
        fu.u[1] = h ? r1 : o1;
        fu.u[2] = h ? o0 : r0;
        fu.u[3] = h ? o1 : r1;
        pfrag[qb][ks] = fu.s;
      }
    }

    #pragma unroll
    for (int db = 0; db < 2; ++db) {
      short8 vf[4];
      #pragma unroll
      for (int ks = 0; ks < 4; ++ks) {
        int row = db * 32 + l31;
        int g = (2 * ks + h) ^ (row & 7);
        vf[ks] = *(const short8*)(ldsV + row * 128 + g * 16);
      }
      __builtin_amdgcn_s_setprio(1);
      #pragma unroll
      for (int qb = 0; qb < 2; ++qb)
        #pragma unroll
        for (int ks = 0; ks < 4; ++ks)
          acc[db][qb] = __builtin_amdgcn_mfma_f32_32x32x16_bf16(
              vf[ks], pfrag[qb][ks], acc[db][qb], 0, 0, 0);
      __builtin_amdgcn_s_setprio(0);
    }

    __syncthreads();
  }

  #pragma unroll
  for (int qb = 0; qb < 2; ++qb) {
    float inv = 1.0f / l_run[qb];
    int q = q0 + qb * 32 + l31;
    float* orow = out + ((long long)b * S_ + q) * H_ + hd * D_;
    #pragma unroll
    for (int db = 0; db < 2; ++db)
      #pragma unroll
      for (int rg = 0; rg < 4; ++rg) {
        f32x4 v4;
        #pragma unroll
        for (int c = 0; c < 4; ++c) v4[c] = acc[db][qb][rg * 4 + c] * inv;
        *(f32x4*)(orow + db * 32 + rg * 8 + 4 * h) = v4;
      }
  }
}

// ---------------- launcher -------------------------------------------------
extern "C" void kernel_launch(void* const* d_in, const int* in_sizes, int n_in,
                              void* d_out, int out_size, void* d_ws, size_t ws_size,
                              hipStream_t stream) {
  const float* X    = (const float*)d_in[0];
  const float* mask = (const float*)d_in[1];
  const float* Wq   = (const float*)d_in[2];
  const float* bq   = (const float*)d_in[3];
  const float* Wk   = (const float*)d_in[4];
  const float* bk   = (const float*)d_in[5];
  const float* Wv   = (const float*)d_in[6];
  const float* bv   = (const float*)d_in[7];
  float* out = (float*)d_out;

  char* ws = (char*)d_ws;
  unsigned short* Xbf = (unsigned short*)ws;                 // 16 MB
  unsigned short* Wbf = (unsigned short*)(ws + 16777216);    //  6 MB
  unsigned short* Qb  = (unsigned short*)(ws + 23068672);    // 16 MB
  unsigned short* Kb  = (unsigned short*)(ws + 39845888);    // 16 MB
  unsigned short* Vt  = (unsigned short*)(ws + 56623104);    // 16 MB

  hipLaunchKernelGGL(cvt_f32_bf16, dim3(2048), dim3(256), 0, stream,
                     X, Wq, Wk, Wv, Xbf, Wbf);
  hipLaunchKernelGGL(qkv_gemm, dim3(768), dim3(512), 0, stream,
                     Xbf, Wbf, bq, bk, bv, Qb, Kb, Vt);
  hipLaunchKernelGGL(attn_fused, dim3(512), dim3(256), 0, stream,
                     Qb, Kb, Vt, mask, out);
}